// Round 9
// baseline (230.202 us; speedup 1.0000x reference)
//
#include <hip/hip_runtime.h>
#include <stdint.h>

// Problem constants (B=2,S=2048 -> BS=4096). ALL inputs/outputs are FP32.
#define BSZ   4096    // B*S tokens
#define DIM   1024    // D
#define WTR   4096    // W trees
#define KDIM  4096    // GEMM K == W
#define W8    32768   // W*8 leaf-rows

typedef unsigned short u16;
typedef __attribute__((ext_vector_type(8))) short bhalf8;     // 8 x bf16 (4 VGPRs)
typedef __attribute__((ext_vector_type(4))) float floatx4;    // 16x16 MFMA acc
typedef __attribute__((ext_vector_type(16))) float floatx16;  // 32x32 MFMA acc

__device__ __forceinline__ u16 f2bf(float f) {
    union { float f; uint32_t i; } v; v.f = f;
    uint32_t r = v.i + 0x7fffu + ((v.i >> 16) & 1u);   // round-nearest-even
    return (u16)(r >> 16);
}
// tanh(x) = 1 - 2/(exp2(x*2*log2e)+1)
__device__ __forceinline__ float fast_tanh(float x) {
    float e = __builtin_amdgcn_exp2f(x * 2.885390081777927f);
    return fmaf(-2.0f, __builtin_amdgcn_rcpf(e + 1.0f), 1.0f);
}
__device__ __forceinline__ void load16(const void* g, void* lds) {
    __builtin_amdgcn_global_load_lds(
        (const __attribute__((address_space(1))) uint32_t*)g,
        (__attribute__((address_space(3))) uint32_t*)lds, 16, 0, 0);
}

#define NB_SEL   128
#define NB_OWT   4096
#define NB_CINIT 256
#define NB_BASIS 256

// ---- kernel 0 (fused prep): selector softmax -> bf16 A (PERMUTED rows);
//      out_w^T bf16; C init = out_b; basis = tanh(hidden@slot_w+b) (MFMA) ------
__global__ __launch_bounds__(256) void k_prep(const float* __restrict__ ll,
                                              u16* __restrict__ selwA,
                                              const float* __restrict__ ow,
                                              u16* __restrict__ owt,
                                              const float* __restrict__ slot_w,
                                              const float* __restrict__ slot_b,
                                              const float* __restrict__ out_b,
                                              float* __restrict__ C,
                                              const float* __restrict__ hidden,
                                              u16* __restrict__ basisTB) {
    __shared__ __align__(16) char smem[20608];
    int bid = blockIdx.x, tid = threadIdx.x;
    if (bid < NB_SEL) {                    // ---- selector: 32768 rows
        int row = bid * 256 + tid;         // w*8 + l
        int w = row >> 3, l = row & 7, q = w & 3;
        int prow = (w >> 2) * 32 + (l & 3) + 8 * (l >> 2) + 16 * (q & 1) + 4 * (q >> 1);
        const float* p = ll + (size_t)row * 11;
        float v[11]; float m = -1e30f;
        #pragma unroll
        for (int c = 0; c < 11; ++c) { v[c] = p[c]; m = fmaxf(m, v[c]); }
        float s = 0.f;
        #pragma unroll
        for (int c = 0; c < 11; ++c) {
            v[c] = __builtin_amdgcn_exp2f((v[c] - m) * 1.4426950408889634f);
            s += v[c];
        }
        float inv = __builtin_amdgcn_rcpf(s);
        union { u16 h[16]; uint4 qq[2]; } o;
        #pragma unroll
        for (int c = 0; c < 8; ++c) o.h[c] = f2bf(v[c] * inv);
        o.h[8] = f2bf((v[10] - v[8]) * inv);   // consts -1,0,1 folded (basis k8=1)
        #pragma unroll
        for (int c = 9; c < 16; ++c) o.h[c] = 0;
        uint4* dst = (uint4*)(selwA + (size_t)prow * 16);
        dst[0] = o.qq[0]; dst[1] = o.qq[1];
    } else if (bid < NB_SEL + NB_OWT) {    // ---- out_w (W,D) -> owt (D,W) bf16
        float (*tile)[33] = (float (*)[33])smem;
        int b = bid - NB_SEL;
        int d0 = (b & 31) * 32, w0 = (b >> 5) * 32;
        int tx = tid & 31, ty = tid >> 5;
        #pragma unroll
        for (int i = 0; i < 32; i += 8)
            tile[ty + i][tx] = ow[(size_t)(w0 + ty + i) * DIM + d0 + tx];
        __syncthreads();
        #pragma unroll
        for (int i = 0; i < 32; i += 8)
            owt[(size_t)(d0 + ty + i) * WTR + w0 + tx] = f2bf(tile[tx][ty + i]);
    } else if (bid < NB_SEL + NB_OWT + NB_CINIT) {   // ---- C init: C[r][n]=out_b[n]
        int b = bid - NB_SEL - NB_OWT;     // 256 blocks x 16 rows
        float4 bv = *(const float4*)(out_b + tid * 4);
        #pragma unroll
        for (int it = 0; it < 16; ++it) {
            size_t flat = (size_t)b * 16384 + it * 1024 + tid * 4;
            *(float4*)(C + flat) = bv;
        }
    } else {                               // ---- basis: 16 tokens/block, MFMA
        u16*   sw  = (u16*)smem;                       // [8][1024] bf16, 16 KB
        float* smr = (float*)(smem + 16384);           // [4][16][16], 4 KB
        int b = bid - NB_SEL - NB_OWT - NB_CINIT;
        int m0 = b * 16;
        for (int i = tid; i < 8 * 1024; i += 256) {
            int d = i & 1023, s = i >> 10;
            sw[s * 1024 + d] = f2bf(slot_w[(size_t)d * 8 + s]);
        }
        __syncthreads();
        int lane = tid & 63, wid = tid >> 6;
        int col = lane & 15, quad = lane >> 4;
        const float* ga = hidden + (size_t)(m0 + col) * DIM + wid * 256 + quad * 8;
        const u16*   gb = sw + (col & 7) * 1024 + wid * 256 + quad * 8;
        bhalf8 zz = {0, 0, 0, 0, 0, 0, 0, 0};
        floatx4 acc = (floatx4){0.f, 0.f, 0.f, 0.f};
        #pragma unroll
        for (int k0 = 0; k0 < 256; k0 += 32) {
            float4 a0 = *(const float4*)(ga + k0);
            float4 a1 = *(const float4*)(ga + k0 + 4);
            bhalf8 bf = *(const bhalf8*)(gb + k0);   // LDS b128
            if (col >= 8) bf = zz;
            bhalf8 af;
            af[0] = (short)f2bf(a0.x); af[1] = (short)f2bf(a0.y);
            af[2] = (short)f2bf(a0.z); af[3] = (short)f2bf(a0.w);
            af[4] = (short)f2bf(a1.x); af[5] = (short)f2bf(a1.y);
            af[6] = (short)f2bf(a1.z); af[7] = (short)f2bf(a1.w);
            acc = __builtin_amdgcn_mfma_f32_16x16x32_bf16(af, bf, acc, 0, 0, 0);
        }
        float (*sm3)[16][16] = (float (*)[16][16])smr;
        #pragma unroll
        for (int r = 0; r < 4; ++r) sm3[wid][quad * 4 + r][col] = acc[r];
        __syncthreads();
        int tt = tid >> 4, cc = tid & 15;
        float s = sm3[0][tt][cc] + sm3[1][tt][cc] + sm3[2][tt][cc] + sm3[3][tt][cc];
        u16 val;
        if (cc < 8)       val = f2bf(fast_tanh(s + slot_b[cc]));
        else if (cc == 8) val = (u16)0x3f80;   // bf16 1.0
        else              val = 0;
        basisTB[(size_t)(m0 + tt) * 16 + cc] = val;
    }
}

// ---- kernel 1: roots via MFMA einsum (permuted A) + in-register tree ---------
// Node refactor: y = 2log2e*x = L*fmaf(A2,R,A1) + fmaf(A3,R,A4);
// tanh = 1 - 2*rcp(exp2(y)+1)
__device__ __forceinline__ float tree_eval(float v[8], float A1, float A2,
                                           float A3, float A4) {
    #pragma unroll
    for (int lev = 0; lev < 3; ++lev) {
        int n = 4 >> lev;
        #pragma unroll
        for (int i = 0; i < 4; ++i) {
            if (i < n) {
                float L = v[2*i], R = v[2*i+1];
                float u = fmaf(A2, R, A1);
                float w = fmaf(A3, R, A4);
                float y = fmaf(L, u, w);
                float e = __builtin_amdgcn_exp2f(y);
                v[i] = fmaf(-2.0f, __builtin_amdgcn_rcpf(e + 1.0f), 1.0f);
            }
        }
    }
    return v[0];
}

__global__ __launch_bounds__(256, 2) void k_roots(const u16* __restrict__ selwA,
                                                  const u16* __restrict__ basisTB,
                                                  const float* __restrict__ np_,
                                                  u16* __restrict__ roots) {
    __shared__ uint32_t st[2][32 * 33];   // [buf][token*33 + pair], stride 33
    int tid = threadIdx.x, wid = tid >> 6, lane = tid & 63;
    int c = lane & 31, h = lane >> 5;
    int tile0 = blockIdx.x * 16 + wid * 4;   // 4 tiles per wave, 16 per block
    int wblk  = blockIdx.x * 64;             // block's first tree
    int t0b   = blockIdx.y * 512;
    float lw = np_[0], rw = np_[1], pw = np_[2], dw = np_[3], nb = np_[4];
    const float c2 = 2.885390081777927f;     // 2*log2(e)
    float A1 = (lw + dw) * c2, A2 = pw * c2, A3 = (rw - dw) * c2, A4 = nb * c2;

    bhalf8 af[4];
    #pragma unroll
    for (int tl = 0; tl < 4; ++tl)
        af[tl] = *(const bhalf8*)(selwA + (size_t)((tile0 + tl) * 32 + c) * 16 + h * 8);

    int tok = tid >> 3, ch = tid & 7;        // store-phase role
    for (int it = 0; it < 16; ++it) {
        int t0 = t0b + it * 32;
        uint32_t* buf = st[it & 1];
        bhalf8 bf = *(const bhalf8*)(basisTB + (size_t)(t0 + c) * 16 + h * 8);
        #pragma unroll
        for (int tl = 0; tl < 4; ++tl) {
            floatx16 z = {0.f,0.f,0.f,0.f,0.f,0.f,0.f,0.f,
                          0.f,0.f,0.f,0.f,0.f,0.f,0.f,0.f};
            floatx16 cc = __builtin_amdgcn_mfma_f32_32x32x16_bf16(af[tl], bf, z, 0, 0, 0);
            float vA[8], vB[8];
            #pragma unroll
            for (int l = 0; l < 8; ++l) { vA[l] = cc[l]; vB[l] = cc[8 + l]; }
            float rA = tree_eval(vA, A1, A2, A3, A4);
            float rB = tree_eval(vB, A1, A2, A3, A4);
            buf[c * 33 + wid * 8 + tl * 2 + h] =
                (uint32_t)f2bf(rA) | ((uint32_t)f2bf(rB) << 16);
        }
        __syncthreads();
        uint32_t d0 = buf[tok * 33 + ch * 4];
        uint32_t d1 = buf[tok * 33 + ch * 4 + 1];
        uint32_t d2 = buf[tok * 33 + ch * 4 + 2];
        uint32_t d3 = buf[tok * 33 + ch * 4 + 3];
        uint4 q; q.x = d0; q.y = d1; q.z = d2; q.w = d3;
        *(uint4*)(roots + (size_t)(t0 + tok) * WTR + wblk + ch * 8) = q;
    }
}

// ---- kernel 2: C += split-K partial of roots @ out_w  (atomic f32) -----------
// m97 geometry: BM=128 BN=128 BK=32 (16 KB LDS), split-K=4 -> grid (32,8,4) =
// 1024 blocks = 4/CU co-resident. Wave tile 64x64: 8 ds_read_b128 per 16 MFMA.
// XOR-swizzled 16B chunks over 4-chunk rows (even 8-lane/bank-group spread).
__global__ __launch_bounds__(256) void k_gemm(const u16* __restrict__ A,
                                              const u16* __restrict__ Bt,
                                              float* __restrict__ C) {
    __shared__ __align__(16) u16 smA[128 * 32];   // 8 KB
    __shared__ __align__(16) u16 smB[128 * 32];   // 8 KB
    int tid = threadIdx.x;
    int bm = blockIdx.x * 128, bn = blockIdx.y * 128;
    int koff = blockIdx.z * (KDIM / 4);
    int lane = tid & 63, wid = tid >> 6;
    int wm = (wid >> 1) * 64, wn = (wid & 1) * 64;

    floatx4 acc[4][4];
    #pragma unroll
    for (int i = 0; i < 4; ++i)
        #pragma unroll
        for (int j = 0; j < 4; ++j) acc[i][j] = (floatx4){0.f, 0.f, 0.f, 0.f};

    int ar = tid >> 2;                         // staging row 0..63 (+64 2nd rep)
    int ak = ((tid & 3) ^ (ar & 3)) * 8;       // swizzled source k-chunk
    const u16* gA = A  + (size_t)(bm + ar) * KDIM + koff + ak;
    const u16* gB = Bt + (size_t)(bn + ar) * KDIM + koff + ak;
    char* ldA = (char*)smA + tid * 16;
    char* ldB = (char*)smB + tid * 16;

    int col = lane & 15, quad = lane >> 4, csw = col & 3;

    for (int k0 = 0; k0 < KDIM / 4; k0 += 32) {
        __syncthreads();                       // prev iter's ds_reads done
        load16(gA,                       ldA);
        load16(gA + (size_t)64 * KDIM,   ldA + 4096);
        load16(gB,                       ldB);
        load16(gB + (size_t)64 * KDIM,   ldB + 4096);
        gA += 32; gB += 32;
        __syncthreads();                       // drain (hidden by 4 blk/CU)

        bhalf8 af[4], bf[4];
        int kchunk = (quad ^ csw) * 8;
        #pragma unroll
        for (int i = 0; i < 4; ++i)
            af[i] = *(const bhalf8*)(smA + (wm + i * 16 + col) * 32 + kchunk);
        #pragma unroll
        for (int j = 0; j < 4; ++j)
            bf[j] = *(const bhalf8*)(smB + (wn + j * 16 + col) * 32 + kchunk);
        #pragma unroll
        for (int i = 0; i < 4; ++i)
            #pragma unroll
            for (int j = 0; j < 4; ++j)
                acc[i][j] = __builtin_amdgcn_mfma_f32_16x16x32_bf16(
                    af[i], bf[j], acc[i][j], 0, 0, 0);
    }

    #pragma unroll
    for (int j = 0; j < 4; ++j) {
        int n = bn + wn + j * 16 + col;
        #pragma unroll
        for (int i = 0; i < 4; ++i) {
            int m0 = bm + wm + i * 16 + quad * 4;
            #pragma unroll
            for (int r = 0; r < 4; ++r)
                atomicAdd(&C[(size_t)(m0 + r) * DIM + n], acc[i][j][r]);
        }
    }
}

// ---------------- launcher ----------------------------------------------------
extern "C" void kernel_launch(void* const* d_in, const int* in_sizes, int n_in,
                              void* d_out, int out_size, void* d_ws, size_t ws_size,
                              hipStream_t stream) {
    const float* hidden      = (const float*)d_in[0];
    const float* slot_w      = (const float*)d_in[1];
    const float* slot_b      = (const float*)d_in[2];
    const float* leaf_logits = (const float*)d_in[3];
    const float* node_params = (const float*)d_in[4];
    const float* out_w       = (const float*)d_in[5];
    const float* out_b       = (const float*)d_in[6];
    float* out = (float*)d_out;

    char* ws = (char*)d_ws;
    u16* selwA   = (u16*)ws;                          // 32768*32B   = 1048576
    u16* basisTB = (u16*)(ws + 1048576);              // 4096*32B    = 131072
    u16* outwt   = (u16*)(ws + 1212416);              // 1024*4096*2 = 8388608
    u16* roots   = (u16*)(ws + 9601024);              // 4096*4096*2 = 33554432

    k_prep <<<NB_SEL + NB_OWT + NB_CINIT + NB_BASIS, 256, 0, stream>>>(
        leaf_logits, selwA, out_w, outwt, slot_w, slot_b, out_b, out, hidden, basisTB);
    k_roots<<<dim3(64, 8), 256, 0, stream>>>(selwA, basisTB, node_params, roots);
    k_gemm <<<dim3(BSZ / 128, DIM / 128, 4), 256, 0, stream>>>(roots, outwt, out);
}

// Round 10
// 219.096 us; speedup vs baseline: 1.0507x; 1.0507x over previous
//
#include <hip/hip_runtime.h>
#include <stdint.h>

// Problem constants (B=2,S=2048 -> BS=4096). ALL inputs/outputs are FP32.
#define BSZ   4096    // B*S tokens
#define DIM   1024    // D
#define WTR   4096    // W trees
#define KDIM  4096    // GEMM K == W
#define W8    32768   // W*8 leaf-rows

typedef unsigned short u16;
typedef __attribute__((ext_vector_type(8))) short bhalf8;     // 8 x bf16 (4 VGPRs)
typedef __attribute__((ext_vector_type(4))) float floatx4;    // 16x16 MFMA acc
typedef __attribute__((ext_vector_type(16))) float floatx16;  // 32x32 MFMA acc

__device__ __forceinline__ u16 f2bf(float f) {
    union { float f; uint32_t i; } v; v.f = f;
    uint32_t r = v.i + 0x7fffu + ((v.i >> 16) & 1u);   // round-nearest-even
    return (u16)(r >> 16);
}
// tanh(x) = 1 - 2/(exp2(x*2*log2e)+1)
__device__ __forceinline__ float fast_tanh(float x) {
    float e = __builtin_amdgcn_exp2f(x * 2.885390081777927f);
    return fmaf(-2.0f, __builtin_amdgcn_rcpf(e + 1.0f), 1.0f);
}
__device__ __forceinline__ void load16(const void* g, void* lds) {
    __builtin_amdgcn_global_load_lds(
        (const __attribute__((address_space(1))) uint32_t*)g,
        (__attribute__((address_space(3))) uint32_t*)lds, 16, 0, 0);
}

#define NB_SEL   128
#define NB_OWT   4096
#define NB_CINIT 256
#define NB_BASIS 256

// ---- kernel 0 (fused prep): selector softmax -> bf16 A (PERMUTED rows);
//      out_w^T bf16; C init = out_b; basis = tanh(hidden@slot_w+b) (MFMA) ------
__global__ __launch_bounds__(256) void k_prep(const float* __restrict__ ll,
                                              u16* __restrict__ selwA,
                                              const float* __restrict__ ow,
                                              u16* __restrict__ owt,
                                              const float* __restrict__ slot_w,
                                              const float* __restrict__ slot_b,
                                              const float* __restrict__ out_b,
                                              float* __restrict__ C,
                                              const float* __restrict__ hidden,
                                              u16* __restrict__ basisTB) {
    __shared__ __align__(16) char smem[20608];
    int bid = blockIdx.x, tid = threadIdx.x;
    if (bid < NB_SEL) {                    // ---- selector: 32768 rows
        int row = bid * 256 + tid;         // w*8 + l
        int w = row >> 3, l = row & 7, q = w & 3;
        int prow = (w >> 2) * 32 + (l & 3) + 8 * (l >> 2) + 16 * (q & 1) + 4 * (q >> 1);
        const float* p = ll + (size_t)row * 11;
        float v[11]; float m = -1e30f;
        #pragma unroll
        for (int c = 0; c < 11; ++c) { v[c] = p[c]; m = fmaxf(m, v[c]); }
        float s = 0.f;
        #pragma unroll
        for (int c = 0; c < 11; ++c) {
            v[c] = __builtin_amdgcn_exp2f((v[c] - m) * 1.4426950408889634f);
            s += v[c];
        }
        float inv = __builtin_amdgcn_rcpf(s);
        union { u16 h[16]; uint4 qq[2]; } o;
        #pragma unroll
        for (int c = 0; c < 8; ++c) o.h[c] = f2bf(v[c] * inv);
        o.h[8] = f2bf((v[10] - v[8]) * inv);   // consts -1,0,1 folded (basis k8=1)
        #pragma unroll
        for (int c = 9; c < 16; ++c) o.h[c] = 0;
        uint4* dst = (uint4*)(selwA + (size_t)prow * 16);
        dst[0] = o.qq[0]; dst[1] = o.qq[1];
    } else if (bid < NB_SEL + NB_OWT) {    // ---- out_w (W,D) -> owt (D,W) bf16
        float (*tile)[33] = (float (*)[33])smem;
        int b = bid - NB_SEL;
        int d0 = (b & 31) * 32, w0 = (b >> 5) * 32;
        int tx = tid & 31, ty = tid >> 5;
        #pragma unroll
        for (int i = 0; i < 32; i += 8)
            tile[ty + i][tx] = ow[(size_t)(w0 + ty + i) * DIM + d0 + tx];
        __syncthreads();
        #pragma unroll
        for (int i = 0; i < 32; i += 8)
            owt[(size_t)(d0 + ty + i) * WTR + w0 + tx] = f2bf(tile[tx][ty + i]);
    } else if (bid < NB_SEL + NB_OWT + NB_CINIT) {   // ---- C init: C[r][n]=out_b[n]
        int b = bid - NB_SEL - NB_OWT;     // 256 blocks x 16 rows
        float4 bv = *(const float4*)(out_b + tid * 4);
        #pragma unroll
        for (int it = 0; it < 16; ++it) {
            size_t flat = (size_t)b * 16384 + it * 1024 + tid * 4;
            *(float4*)(C + flat) = bv;
        }
    } else {                               // ---- basis: 16 tokens/block, MFMA
        u16*   sw  = (u16*)smem;                       // [8][1024] bf16, 16 KB
        float* smr = (float*)(smem + 16384);           // [4][16][16], 4 KB
        int b = bid - NB_SEL - NB_OWT - NB_CINIT;
        int m0 = b * 16;
        for (int i = tid; i < 8 * 1024; i += 256) {
            int d = i & 1023, s = i >> 10;
            sw[s * 1024 + d] = f2bf(slot_w[(size_t)d * 8 + s]);
        }
        __syncthreads();
        int lane = tid & 63, wid = tid >> 6;
        int col = lane & 15, quad = lane >> 4;
        const float* ga = hidden + (size_t)(m0 + col) * DIM + wid * 256 + quad * 8;
        const u16*   gb = sw + (col & 7) * 1024 + wid * 256 + quad * 8;
        bhalf8 zz = {0, 0, 0, 0, 0, 0, 0, 0};
        floatx4 acc = (floatx4){0.f, 0.f, 0.f, 0.f};
        #pragma unroll
        for (int k0 = 0; k0 < 256; k0 += 32) {
            float4 a0 = *(const float4*)(ga + k0);
            float4 a1 = *(const float4*)(ga + k0 + 4);
            bhalf8 bf = *(const bhalf8*)(gb + k0);   // LDS b128
            if (col >= 8) bf = zz;
            bhalf8 af;
            af[0] = (short)f2bf(a0.x); af[1] = (short)f2bf(a0.y);
            af[2] = (short)f2bf(a0.z); af[3] = (short)f2bf(a0.w);
            af[4] = (short)f2bf(a1.x); af[5] = (short)f2bf(a1.y);
            af[6] = (short)f2bf(a1.z); af[7] = (short)f2bf(a1.w);
            acc = __builtin_amdgcn_mfma_f32_16x16x32_bf16(af, bf, acc, 0, 0, 0);
        }
        float (*sm3)[16][16] = (float (*)[16][16])smr;
        #pragma unroll
        for (int r = 0; r < 4; ++r) sm3[wid][quad * 4 + r][col] = acc[r];
        __syncthreads();
        int tt = tid >> 4, cc = tid & 15;
        float s = sm3[0][tt][cc] + sm3[1][tt][cc] + sm3[2][tt][cc] + sm3[3][tt][cc];
        u16 val;
        if (cc < 8)       val = f2bf(fast_tanh(s + slot_b[cc]));
        else if (cc == 8) val = (u16)0x3f80;   // bf16 1.0
        else              val = 0;
        basisTB[(size_t)(m0 + tt) * 16 + cc] = val;
    }
}

// ---- kernel 1: roots via MFMA einsum (permuted A) + in-register tree ---------
__device__ __forceinline__ float tree_eval(float v[8], float A1, float A2,
                                           float A3, float A4) {
    #pragma unroll
    for (int lev = 0; lev < 3; ++lev) {
        int n = 4 >> lev;
        #pragma unroll
        for (int i = 0; i < 4; ++i) {
            if (i < n) {
                float L = v[2*i], R = v[2*i+1];
                float u = fmaf(A2, R, A1);
                float w = fmaf(A3, R, A4);
                float y = fmaf(L, u, w);
                float e = __builtin_amdgcn_exp2f(y);
                v[i] = fmaf(-2.0f, __builtin_amdgcn_rcpf(e + 1.0f), 1.0f);
            }
        }
    }
    return v[0];
}

__global__ __launch_bounds__(256, 2) void k_roots(const u16* __restrict__ selwA,
                                                  const u16* __restrict__ basisTB,
                                                  const float* __restrict__ np_,
                                                  u16* __restrict__ roots) {
    __shared__ uint32_t st[2][32 * 33];   // [buf][token*33 + pair], stride 33
    int tid = threadIdx.x, wid = tid >> 6, lane = tid & 63;
    int c = lane & 31, h = lane >> 5;
    int tile0 = blockIdx.x * 16 + wid * 4;   // 4 tiles per wave, 16 per block
    int wblk  = blockIdx.x * 64;             // block's first tree
    int t0b   = blockIdx.y * 512;
    float lw = np_[0], rw = np_[1], pw = np_[2], dw = np_[3], nb = np_[4];
    const float c2 = 2.885390081777927f;     // 2*log2(e)
    float A1 = (lw + dw) * c2, A2 = pw * c2, A3 = (rw - dw) * c2, A4 = nb * c2;

    bhalf8 af[4];
    #pragma unroll
    for (int tl = 0; tl < 4; ++tl)
        af[tl] = *(const bhalf8*)(selwA + (size_t)((tile0 + tl) * 32 + c) * 16 + h * 8);

    int tok = tid >> 3, ch = tid & 7;        // store-phase role
    for (int it = 0; it < 16; ++it) {
        int t0 = t0b + it * 32;
        uint32_t* buf = st[it & 1];
        bhalf8 bf = *(const bhalf8*)(basisTB + (size_t)(t0 + c) * 16 + h * 8);
        #pragma unroll
        for (int tl = 0; tl < 4; ++tl) {
            floatx16 z = {0.f,0.f,0.f,0.f,0.f,0.f,0.f,0.f,
                          0.f,0.f,0.f,0.f,0.f,0.f,0.f,0.f};
            floatx16 cc = __builtin_amdgcn_mfma_f32_32x32x16_bf16(af[tl], bf, z, 0, 0, 0);
            float vA[8], vB[8];
            #pragma unroll
            for (int l = 0; l < 8; ++l) { vA[l] = cc[l]; vB[l] = cc[8 + l]; }
            float rA = tree_eval(vA, A1, A2, A3, A4);
            float rB = tree_eval(vB, A1, A2, A3, A4);
            buf[c * 33 + wid * 8 + tl * 2 + h] =
                (uint32_t)f2bf(rA) | ((uint32_t)f2bf(rB) << 16);
        }
        __syncthreads();
        uint32_t d0 = buf[tok * 33 + ch * 4];
        uint32_t d1 = buf[tok * 33 + ch * 4 + 1];
        uint32_t d2 = buf[tok * 33 + ch * 4 + 2];
        uint32_t d3 = buf[tok * 33 + ch * 4 + 3];
        uint4 q; q.x = d0; q.y = d1; q.z = d2; q.w = d3;
        *(uint4*)(roots + (size_t)(t0 + tok) * WTR + wblk + ch * 8) = q;
    }
}

// ---- kernel 2: C += split-K partial of roots @ out_w  (atomic f32) -----------
// BM=128 BN=128 BK=32 (16 KB LDS), 128-thr blocks (2 waves), wave tile 64x128:
// 12 ds_read_b128 per 32 MFMA (144 vs 155 cyc -> MFMA-bound). split-K=4 ->
// 1024 blocks = 4/CU. Block-id swizzle co-locates the 4 split-z partials of a
// C tile on one XCD (ids share %8) so f32 atomics stay in local L2.
// Correct BK=32 swizzle: chunk = quad ^ ((col>>1)&3)  (col&1 = bank parity bit
// must stay OUT of the XOR; R4/R5/R6/R9 conflict counts all fit this model).
__global__ __launch_bounds__(128, 2) void k_gemm(const u16* __restrict__ A,
                                                 const u16* __restrict__ Bt,
                                                 float* __restrict__ C) {
    __shared__ __align__(16) u16 smA[128 * 32];   // 8 KB
    __shared__ __align__(16) u16 smB[128 * 32];   // 8 KB
    int tid = threadIdx.x;
    int id = blockIdx.x;
    int xcd = id & 7, rest = id >> 3;
    int z = rest & 3;
    int tile = (rest >> 2) * 8 + xcd;     // [0,256)
    int bm = (tile & 31) * 128;
    int bn = (tile >> 5) * 128;
    int koff = z * (KDIM / 4);
    int lane = tid & 63, wid = tid >> 6;  // 2 waves
    int wm = wid * 64;

    floatx4 acc[4][8];
    #pragma unroll
    for (int i = 0; i < 4; ++i)
        #pragma unroll
        for (int j = 0; j < 8; ++j) acc[i][j] = (floatx4){0.f, 0.f, 0.f, 0.f};

    int ar = tid >> 2;                          // staging row 0..31 (+32/rep)
    int ak = ((tid & 3) ^ ((ar >> 1) & 3)) * 8; // swizzled source k-chunk
    const u16* gA = A  + (size_t)(bm + ar) * KDIM + koff + ak;
    const u16* gB = Bt + (size_t)(bn + ar) * KDIM + koff + ak;
    char* ldA = (char*)smA + tid * 16;
    char* ldB = (char*)smB + tid * 16;

    int col = lane & 15, quad = lane >> 4;
    int kchunk = (quad ^ ((col >> 1) & 3)) * 8;

    for (int k0 = 0; k0 < KDIM / 4; k0 += 32) {
        __syncthreads();                        // prev iter's ds_reads done
        load16(gA,                       ldA);
        load16(gA + (size_t)32 * KDIM,   ldA + 2048);
        load16(gA + (size_t)64 * KDIM,   ldA + 4096);
        load16(gA + (size_t)96 * KDIM,   ldA + 6144);
        load16(gB,                       ldB);
        load16(gB + (size_t)32 * KDIM,   ldB + 2048);
        load16(gB + (size_t)64 * KDIM,   ldB + 4096);
        load16(gB + (size_t)96 * KDIM,   ldB + 6144);
        gA += 32; gB += 32;
        __syncthreads();                        // drain (hidden by 4 blk/CU)

        bhalf8 af[4], bf[8];
        #pragma unroll
        for (int i = 0; i < 4; ++i)
            af[i] = *(const bhalf8*)(smA + (wm + i * 16 + col) * 32 + kchunk);
        #pragma unroll
        for (int j = 0; j < 8; ++j)
            bf[j] = *(const bhalf8*)(smB + (j * 16 + col) * 32 + kchunk);
        #pragma unroll
        for (int i = 0; i < 4; ++i)
            #pragma unroll
            for (int j = 0; j < 8; ++j)
                acc[i][j] = __builtin_amdgcn_mfma_f32_16x16x32_bf16(
                    af[i], bf[j], acc[i][j], 0, 0, 0);
    }

    #pragma unroll
    for (int j = 0; j < 8; ++j) {
        int n = bn + j * 16 + col;
        #pragma unroll
        for (int i = 0; i < 4; ++i) {
            int m0 = bm + wm + i * 16 + quad * 4;
            #pragma unroll
            for (int r = 0; r < 4; ++r)
                atomicAdd(&C[(size_t)(m0 + r) * DIM + n], acc[i][j][r]);
        }
    }
}

// ---------------- launcher ----------------------------------------------------
extern "C" void kernel_launch(void* const* d_in, const int* in_sizes, int n_in,
                              void* d_out, int out_size, void* d_ws, size_t ws_size,
                              hipStream_t stream) {
    const float* hidden      = (const float*)d_in[0];
    const float* slot_w      = (const float*)d_in[1];
    const float* slot_b      = (const float*)d_in[2];
    const float* leaf_logits = (const float*)d_in[3];
    const float* node_params = (const float*)d_in[4];
    const float* out_w       = (const float*)d_in[5];
    const float* out_b       = (const float*)d_in[6];
    float* out = (float*)d_out;

    char* ws = (char*)d_ws;
    u16* selwA   = (u16*)ws;                          // 32768*32B   = 1048576
    u16* basisTB = (u16*)(ws + 1048576);              // 4096*32B    = 131072
    u16* outwt   = (u16*)(ws + 1212416);              // 1024*4096*2 = 8388608
    u16* roots   = (u16*)(ws + 9601024);              // 4096*4096*2 = 33554432

    k_prep <<<NB_SEL + NB_OWT + NB_CINIT + NB_BASIS, 256, 0, stream>>>(
        leaf_logits, selwA, out_w, outwt, slot_w, slot_b, out_b, out, hidden, basisTB);
    k_roots<<<dim3(64, 8), 256, 0, stream>>>(selwA, basisTB, node_params, roots);
    k_gemm <<<1024, 128, 0, stream>>>(roots, outwt, out);
}

// Round 11
// 182.272 us; speedup vs baseline: 1.2630x; 1.2020x over previous
//
#include <hip/hip_runtime.h>
#include <stdint.h>

// Problem constants (B=2,S=2048 -> BS=4096). ALL inputs/outputs are FP32.
#define BSZ   4096    // B*S tokens
#define DIM   1024    // D
#define WTR   4096    // W trees
#define KDIM  4096    // GEMM K == W
#define W8    32768   // W*8 leaf-rows

typedef unsigned short u16;
typedef __attribute__((ext_vector_type(8))) short bhalf8;     // 8 x bf16 (4 VGPRs)
typedef __attribute__((ext_vector_type(4))) float floatx4;    // 16x16 MFMA acc
typedef __attribute__((ext_vector_type(16))) float floatx16;  // 32x32 MFMA acc

__device__ __forceinline__ u16 f2bf(float f) {
    union { float f; uint32_t i; } v; v.f = f;
    uint32_t r = v.i + 0x7fffu + ((v.i >> 16) & 1u);   // round-nearest-even
    return (u16)(r >> 16);
}
// tanh(x) = 1 - 2/(exp2(x*2*log2e)+1)
__device__ __forceinline__ float fast_tanh(float x) {
    float e = __builtin_amdgcn_exp2f(x * 2.885390081777927f);
    return fmaf(-2.0f, __builtin_amdgcn_rcpf(e + 1.0f), 1.0f);
}
__device__ __forceinline__ void load16(const void* g, void* lds) {
    __builtin_amdgcn_global_load_lds(
        (const __attribute__((address_space(1))) uint32_t*)g,
        (__attribute__((address_space(3))) uint32_t*)lds, 16, 0, 0);
}

#define NB_SEL   128
#define NB_OWT   4096
#define NB_BASIS 256

// ---- kernel 0 (fused prep): selector softmax -> bf16 A (PERMUTED rows);
//      out_w^T bf16; basis = tanh(hidden@slot_w+b) (MFMA). No C-init needed ----
__global__ __launch_bounds__(256) void k_prep(const float* __restrict__ ll,
                                              u16* __restrict__ selwA,
                                              const float* __restrict__ ow,
                                              u16* __restrict__ owt,
                                              const float* __restrict__ slot_w,
                                              const float* __restrict__ slot_b,
                                              const float* __restrict__ hidden,
                                              u16* __restrict__ basisTB) {
    __shared__ __align__(16) char smem[20608];
    int bid = blockIdx.x, tid = threadIdx.x;
    if (bid < NB_SEL) {                    // ---- selector: 32768 rows
        int row = bid * 256 + tid;         // w*8 + l
        int w = row >> 3, l = row & 7, q = w & 3;
        int prow = (w >> 2) * 32 + (l & 3) + 8 * (l >> 2) + 16 * (q & 1) + 4 * (q >> 1);
        const float* p = ll + (size_t)row * 11;
        float v[11]; float m = -1e30f;
        #pragma unroll
        for (int c = 0; c < 11; ++c) { v[c] = p[c]; m = fmaxf(m, v[c]); }
        float s = 0.f;
        #pragma unroll
        for (int c = 0; c < 11; ++c) {
            v[c] = __builtin_amdgcn_exp2f((v[c] - m) * 1.4426950408889634f);
            s += v[c];
        }
        float inv = __builtin_amdgcn_rcpf(s);
        union { u16 h[16]; uint4 qq[2]; } o;
        #pragma unroll
        for (int c = 0; c < 8; ++c) o.h[c] = f2bf(v[c] * inv);
        o.h[8] = f2bf((v[10] - v[8]) * inv);   // consts -1,0,1 folded (basis k8=1)
        #pragma unroll
        for (int c = 9; c < 16; ++c) o.h[c] = 0;
        uint4* dst = (uint4*)(selwA + (size_t)prow * 16);
        dst[0] = o.qq[0]; dst[1] = o.qq[1];
    } else if (bid < NB_SEL + NB_OWT) {    // ---- out_w (W,D) -> owt (D,W) bf16
        float (*tile)[33] = (float (*)[33])smem;
        int b = bid - NB_SEL;
        int d0 = (b & 31) * 32, w0 = (b >> 5) * 32;
        int tx = tid & 31, ty = tid >> 5;
        #pragma unroll
        for (int i = 0; i < 32; i += 8)
            tile[ty + i][tx] = ow[(size_t)(w0 + ty + i) * DIM + d0 + tx];
        __syncthreads();
        #pragma unroll
        for (int i = 0; i < 32; i += 8)
            owt[(size_t)(d0 + ty + i) * WTR + w0 + tx] = f2bf(tile[tx][ty + i]);
    } else {                               // ---- basis: 16 tokens/block, MFMA
        u16*   sw  = (u16*)smem;                       // [8][1024] bf16, 16 KB
        float* smr = (float*)(smem + 16384);           // [4][16][16], 4 KB
        int b = bid - NB_SEL - NB_OWT;
        int m0 = b * 16;
        for (int i = tid; i < 8 * 1024; i += 256) {
            int d = i & 1023, s = i >> 10;
            sw[s * 1024 + d] = f2bf(slot_w[(size_t)d * 8 + s]);
        }
        __syncthreads();
        int lane = tid & 63, wid = tid >> 6;
        int col = lane & 15, quad = lane >> 4;
        const float* ga = hidden + (size_t)(m0 + col) * DIM + wid * 256 + quad * 8;
        const u16*   gb = sw + (col & 7) * 1024 + wid * 256 + quad * 8;
        bhalf8 zz = {0, 0, 0, 0, 0, 0, 0, 0};
        floatx4 acc = (floatx4){0.f, 0.f, 0.f, 0.f};
        #pragma unroll
        for (int k0 = 0; k0 < 256; k0 += 32) {
            float4 a0 = *(const float4*)(ga + k0);
            float4 a1 = *(const float4*)(ga + k0 + 4);
            bhalf8 bf = *(const bhalf8*)(gb + k0);   // LDS b128
            if (col >= 8) bf = zz;
            bhalf8 af;
            af[0] = (short)f2bf(a0.x); af[1] = (short)f2bf(a0.y);
            af[2] = (short)f2bf(a0.z); af[3] = (short)f2bf(a0.w);
            af[4] = (short)f2bf(a1.x); af[5] = (short)f2bf(a1.y);
            af[6] = (short)f2bf(a1.z); af[7] = (short)f2bf(a1.w);
            acc = __builtin_amdgcn_mfma_f32_16x16x32_bf16(af, bf, acc, 0, 0, 0);
        }
        float (*sm3)[16][16] = (float (*)[16][16])smr;
        #pragma unroll
        for (int r = 0; r < 4; ++r) sm3[wid][quad * 4 + r][col] = acc[r];
        __syncthreads();
        int tt = tid >> 4, cc = tid & 15;
        float s = sm3[0][tt][cc] + sm3[1][tt][cc] + sm3[2][tt][cc] + sm3[3][tt][cc];
        u16 val;
        if (cc < 8)       val = f2bf(fast_tanh(s + slot_b[cc]));
        else if (cc == 8) val = (u16)0x3f80;   // bf16 1.0
        else              val = 0;
        basisTB[(size_t)(m0 + tt) * 16 + cc] = val;
    }
}

// ---- kernel 1: roots via MFMA einsum (permuted A) + in-register tree ---------
__device__ __forceinline__ float tree_eval(float v[8], float A1, float A2,
                                           float A3, float A4) {
    #pragma unroll
    for (int lev = 0; lev < 3; ++lev) {
        int n = 4 >> lev;
        #pragma unroll
        for (int i = 0; i < 4; ++i) {
            if (i < n) {
                float L = v[2*i], R = v[2*i+1];
                float u = fmaf(A2, R, A1);
                float w = fmaf(A3, R, A4);
                float y = fmaf(L, u, w);
                float e = __builtin_amdgcn_exp2f(y);
                v[i] = fmaf(-2.0f, __builtin_amdgcn_rcpf(e + 1.0f), 1.0f);
            }
        }
    }
    return v[0];
}

__global__ __launch_bounds__(256, 2) void k_roots(const u16* __restrict__ selwA,
                                                  const u16* __restrict__ basisTB,
                                                  const float* __restrict__ np_,
                                                  u16* __restrict__ roots) {
    __shared__ uint32_t st[2][32 * 33];   // [buf][token*33 + pair], stride 33
    int tid = threadIdx.x, wid = tid >> 6, lane = tid & 63;
    int c = lane & 31, h = lane >> 5;
    int tile0 = blockIdx.x * 16 + wid * 4;   // 4 tiles per wave, 16 per block
    int wblk  = blockIdx.x * 64;             // block's first tree
    int t0b   = blockIdx.y * 512;
    float lw = np_[0], rw = np_[1], pw = np_[2], dw = np_[3], nb = np_[4];
    const float c2 = 2.885390081777927f;     // 2*log2(e)
    float A1 = (lw + dw) * c2, A2 = pw * c2, A3 = (rw - dw) * c2, A4 = nb * c2;

    bhalf8 af[4];
    #pragma unroll
    for (int tl = 0; tl < 4; ++tl)
        af[tl] = *(const bhalf8*)(selwA + (size_t)((tile0 + tl) * 32 + c) * 16 + h * 8);

    int tok = tid >> 3, ch = tid & 7;        // store-phase role
    for (int it = 0; it < 16; ++it) {
        int t0 = t0b + it * 32;
        uint32_t* buf = st[it & 1];
        bhalf8 bf = *(const bhalf8*)(basisTB + (size_t)(t0 + c) * 16 + h * 8);
        #pragma unroll
        for (int tl = 0; tl < 4; ++tl) {
            floatx16 z = {0.f,0.f,0.f,0.f,0.f,0.f,0.f,0.f,
                          0.f,0.f,0.f,0.f,0.f,0.f,0.f,0.f};
            floatx16 cc = __builtin_amdgcn_mfma_f32_32x32x16_bf16(af[tl], bf, z, 0, 0, 0);
            float vA[8], vB[8];
            #pragma unroll
            for (int l = 0; l < 8; ++l) { vA[l] = cc[l]; vB[l] = cc[8 + l]; }
            float rA = tree_eval(vA, A1, A2, A3, A4);
            float rB = tree_eval(vB, A1, A2, A3, A4);
            buf[c * 33 + wid * 8 + tl * 2 + h] =
                (uint32_t)f2bf(rA) | ((uint32_t)f2bf(rB) << 16);
        }
        __syncthreads();
        uint32_t d0 = buf[tok * 33 + ch * 4];
        uint32_t d1 = buf[tok * 33 + ch * 4 + 1];
        uint32_t d2 = buf[tok * 33 + ch * 4 + 2];
        uint32_t d3 = buf[tok * 33 + ch * 4 + 3];
        uint4 q; q.x = d0; q.y = d1; q.z = d2; q.w = d3;
        *(uint4*)(roots + (size_t)(t0 + tok) * WTR + wblk + ch * 8) = q;
    }
}

// ---- kernel 2: out = roots @ out_w + out_b  (plain stores, NO split-K) -------
// BM=64 BN=64 BK=64, 128-thr blocks (2 waves, wave tile 64x32), 16 KB LDS ->
// grid (64,16) = 1024 blocks = 4/CU naturally, zero atomics, zero C-init.
// A/B re-reads (x16 / x64) land in L2/L3 (roots 33 MB < LIC, owt 8 MB).
// R6-verified zero-conflict swizzle: LDS[r][p] = glob[r][p^(r&7)], 8 chunks/row.
__global__ __launch_bounds__(128) void k_gemm(const u16* __restrict__ A,
                                              const u16* __restrict__ Bt,
                                              const float* __restrict__ out_b,
                                              float* __restrict__ C) {
    __shared__ __align__(16) u16 smA[64 * 64];    // 8 KB
    __shared__ __align__(16) u16 smB[64 * 64];    // 8 KB
    int tid = threadIdx.x;
    int bm = blockIdx.x * 64, bn = blockIdx.y * 64;
    int lane = tid & 63, wid = tid >> 6;   // 2 waves
    int wn = wid * 32;

    floatx4 acc[4][2];
    #pragma unroll
    for (int i = 0; i < 4; ++i)
        #pragma unroll
        for (int j = 0; j < 2; ++j) acc[i][j] = (floatx4){0.f, 0.f, 0.f, 0.f};

    int ar = tid >> 3;                          // staging row 0..15 (+16/inst)
    int ak = ((tid & 7) ^ (ar & 7)) * 8;        // swizzled source k-chunk
    const u16* gA = A  + (size_t)(bm + ar) * KDIM + ak;
    const u16* gB = Bt + (size_t)(bn + ar) * KDIM + ak;
    char* ldA = (char*)smA + tid * 16;
    char* ldB = (char*)smB + tid * 16;

    int col = lane & 15, quad = lane >> 4, csw = col & 7;

    for (int k0 = 0; k0 < KDIM; k0 += 64) {
        __syncthreads();                        // prev iter's ds_reads done
        load16(gA,                       ldA);
        load16(gA + (size_t)16 * KDIM,   ldA + 2048);
        load16(gA + (size_t)32 * KDIM,   ldA + 4096);
        load16(gA + (size_t)48 * KDIM,   ldA + 6144);
        load16(gB,                       ldB);
        load16(gB + (size_t)16 * KDIM,   ldB + 2048);
        load16(gB + (size_t)32 * KDIM,   ldB + 4096);
        load16(gB + (size_t)48 * KDIM,   ldB + 6144);
        gA += 64; gB += 64;
        __syncthreads();                        // drain (hidden by 4 blk/CU)

        #pragma unroll
        for (int kk = 0; kk < 2; ++kk) {
            int kc = kk * 4 + quad;
            bhalf8 af[4], bf[2];
            #pragma unroll
            for (int i = 0; i < 4; ++i)
                af[i] = *(const bhalf8*)(smA + ((i * 16 + col) * 8 + (kc ^ csw)) * 8);
            #pragma unroll
            for (int j = 0; j < 2; ++j)
                bf[j] = *(const bhalf8*)(smB + ((wn + j * 16 + col) * 8 + (kc ^ csw)) * 8);
            #pragma unroll
            for (int i = 0; i < 4; ++i)
                #pragma unroll
                for (int j = 0; j < 2; ++j)
                    acc[i][j] = __builtin_amdgcn_mfma_f32_16x16x32_bf16(
                        af[i], bf[j], acc[i][j], 0, 0, 0);
        }
    }

    #pragma unroll
    for (int j = 0; j < 2; ++j) {
        int n = bn + wn + j * 16 + col;
        float bv = out_b[n];
        #pragma unroll
        for (int i = 0; i < 4; ++i) {
            int m0 = bm + i * 16 + quad * 4;
            #pragma unroll
            for (int r = 0; r < 4; ++r)
                C[(size_t)(m0 + r) * DIM + n] = acc[i][j][r] + bv;
        }
    }
}

// ---------------- launcher ----------------------------------------------------
extern "C" void kernel_launch(void* const* d_in, const int* in_sizes, int n_in,
                              void* d_out, int out_size, void* d_ws, size_t ws_size,
                              hipStream_t stream) {
    const float* hidden      = (const float*)d_in[0];
    const float* slot_w      = (const float*)d_in[1];
    const float* slot_b      = (const float*)d_in[2];
    const float* leaf_logits = (const float*)d_in[3];
    const float* node_params = (const float*)d_in[4];
    const float* out_w       = (const float*)d_in[5];
    const float* out_b       = (const float*)d_in[6];
    float* out = (float*)d_out;

    char* ws = (char*)d_ws;
    u16* selwA   = (u16*)ws;                          // 32768*32B   = 1048576
    u16* basisTB = (u16*)(ws + 1048576);              // 4096*32B    = 131072
    u16* outwt   = (u16*)(ws + 1212416);              // 1024*4096*2 = 8388608
    u16* roots   = (u16*)(ws + 9601024);              // 4096*4096*2 = 33554432

    k_prep <<<NB_SEL + NB_OWT + NB_BASIS, 256, 0, stream>>>(
        leaf_logits, selwA, out_w, outwt, slot_w, slot_b, hidden, basisTB);
    k_roots<<<dim3(64, 8), 256, 0, stream>>>(selwA, basisTB, node_params, roots);
    k_gemm <<<dim3(BSZ / 64, DIM / 64), 128, 0, stream>>>(roots, outwt, out_b, out);
}

// Round 12
// 171.480 us; speedup vs baseline: 1.3424x; 1.0629x over previous
//
#include <hip/hip_runtime.h>
#include <stdint.h>

// Problem constants (B=2,S=2048 -> BS=4096). ALL inputs/outputs are FP32.
#define BSZ   4096    // B*S tokens
#define DIM   1024    // D
#define WTR   4096    // W trees
#define KDIM  4096    // GEMM K == W
#define W8    32768   // W*8 leaf-rows

typedef unsigned short u16;
typedef __attribute__((ext_vector_type(8))) short bhalf8;     // 8 x bf16 (4 VGPRs)
typedef __attribute__((ext_vector_type(4))) float floatx4;    // 16x16 MFMA acc
typedef __attribute__((ext_vector_type(16))) float floatx16;  // 32x32 MFMA acc

__device__ __forceinline__ u16 f2bf(float f) {
    union { float f; uint32_t i; } v; v.f = f;
    uint32_t r = v.i + 0x7fffu + ((v.i >> 16) & 1u);   // round-nearest-even
    return (u16)(r >> 16);
}
// tanh(x) = 1 - 2/(exp2(x*2*log2e)+1)
__device__ __forceinline__ float fast_tanh(float x) {
    float e = __builtin_amdgcn_exp2f(x * 2.885390081777927f);
    return fmaf(-2.0f, __builtin_amdgcn_rcpf(e + 1.0f), 1.0f);
}
__device__ __forceinline__ void load16(const void* g, void* lds) {
    __builtin_amdgcn_global_load_lds(
        (const __attribute__((address_space(1))) uint32_t*)g,
        (__attribute__((address_space(3))) uint32_t*)lds, 16, 0, 0);
}

#define NB_SEL   128
#define NB_BASIS 256
#define NB_ROOTS 512
#define NB_OWT   1024

// ---- kernel 0 (prep): selector softmax -> bf16 A (PERMUTED rows); basis ------
__global__ __launch_bounds__(256) void k_prep(const float* __restrict__ ll,
                                              u16* __restrict__ selwA,
                                              const float* __restrict__ slot_w,
                                              const float* __restrict__ slot_b,
                                              const float* __restrict__ hidden,
                                              u16* __restrict__ basisTB) {
    __shared__ __align__(16) char smem[20608];
    int bid = blockIdx.x, tid = threadIdx.x;
    if (bid < NB_SEL) {                    // ---- selector: 32768 rows
        int row = bid * 256 + tid;         // w*8 + l
        int w = row >> 3, l = row & 7, q = w & 3;
        int prow = (w >> 2) * 32 + (l & 3) + 8 * (l >> 2) + 16 * (q & 1) + 4 * (q >> 1);
        const float* p = ll + (size_t)row * 11;
        float v[11]; float m = -1e30f;
        #pragma unroll
        for (int c = 0; c < 11; ++c) { v[c] = p[c]; m = fmaxf(m, v[c]); }
        float s = 0.f;
        #pragma unroll
        for (int c = 0; c < 11; ++c) {
            v[c] = __builtin_amdgcn_exp2f((v[c] - m) * 1.4426950408889634f);
            s += v[c];
        }
        float inv = __builtin_amdgcn_rcpf(s);
        union { u16 h[16]; uint4 qq[2]; } o;
        #pragma unroll
        for (int c = 0; c < 8; ++c) o.h[c] = f2bf(v[c] * inv);
        o.h[8] = f2bf((v[10] - v[8]) * inv);   // consts -1,0,1 folded (basis k8=1)
        #pragma unroll
        for (int c = 9; c < 16; ++c) o.h[c] = 0;
        uint4* dst = (uint4*)(selwA + (size_t)prow * 16);
        dst[0] = o.qq[0]; dst[1] = o.qq[1];
    } else {                               // ---- basis: 16 tokens/block, MFMA
        u16*   sw  = (u16*)smem;                       // [8][1024] bf16, 16 KB
        float* smr = (float*)(smem + 16384);           // [4][16][16], 4 KB
        int b = bid - NB_SEL;
        int m0 = b * 16;
        for (int i = tid; i < 8 * 1024; i += 256) {
            int d = i & 1023, s = i >> 10;
            sw[s * 1024 + d] = f2bf(slot_w[(size_t)d * 8 + s]);
        }
        __syncthreads();
        int lane = tid & 63, wid = tid >> 6;
        int col = lane & 15, quad = lane >> 4;
        const float* ga = hidden + (size_t)(m0 + col) * DIM + wid * 256 + quad * 8;
        const u16*   gb = sw + (col & 7) * 1024 + wid * 256 + quad * 8;
        bhalf8 zz = {0, 0, 0, 0, 0, 0, 0, 0};
        floatx4 acc = (floatx4){0.f, 0.f, 0.f, 0.f};
        #pragma unroll
        for (int k0 = 0; k0 < 256; k0 += 32) {
            float4 a0 = *(const float4*)(ga + k0);
            float4 a1 = *(const float4*)(ga + k0 + 4);
            bhalf8 bf = *(const bhalf8*)(gb + k0);   // LDS b128
            if (col >= 8) bf = zz;
            bhalf8 af;
            af[0] = (short)f2bf(a0.x); af[1] = (short)f2bf(a0.y);
            af[2] = (short)f2bf(a0.z); af[3] = (short)f2bf(a0.w);
            af[4] = (short)f2bf(a1.x); af[5] = (short)f2bf(a1.y);
            af[6] = (short)f2bf(a1.z); af[7] = (short)f2bf(a1.w);
            acc = __builtin_amdgcn_mfma_f32_16x16x32_bf16(af, bf, acc, 0, 0, 0);
        }
        float (*sm3)[16][16] = (float (*)[16][16])smr;
        #pragma unroll
        for (int r = 0; r < 4; ++r) sm3[wid][quad * 4 + r][col] = acc[r];
        __syncthreads();
        int tt = tid >> 4, cc = tid & 15;
        float s = sm3[0][tt][cc] + sm3[1][tt][cc] + sm3[2][tt][cc] + sm3[3][tt][cc];
        u16 val;
        if (cc < 8)       val = f2bf(fast_tanh(s + slot_b[cc]));
        else if (cc == 8) val = (u16)0x3f80;   // bf16 1.0
        else              val = 0;
        basisTB[(size_t)(m0 + tt) * 16 + cc] = val;
    }
}

// ---- kernel 1: roots (MFMA einsum + tree, BARRIER-FREE wave-local repack)
//      + owt transpose blocks overlapped in the same grid ---------------------
__device__ __forceinline__ float tree_eval(float v[8], float A1, float A2,
                                           float A3, float A4) {
    #pragma unroll
    for (int lev = 0; lev < 3; ++lev) {
        int n = 4 >> lev;
        #pragma unroll
        for (int i = 0; i < 4; ++i) {
            if (i < n) {
                float L = v[2*i], R = v[2*i+1];
                float u = fmaf(A2, R, A1);
                float w = fmaf(A3, R, A4);
                float y = fmaf(L, u, w);
                float e = __builtin_amdgcn_exp2f(y);
                v[i] = fmaf(-2.0f, __builtin_amdgcn_rcpf(e + 1.0f), 1.0f);
            }
        }
    }
    return v[0];
}

__global__ __launch_bounds__(256, 2) void k_roots(const u16* __restrict__ selwA,
                                                  const u16* __restrict__ basisTB,
                                                  const float* __restrict__ np_,
                                                  u16* __restrict__ roots,
                                                  const float* __restrict__ ow,
                                                  u16* __restrict__ owt) {
    __shared__ __align__(16) char smem[16640];
    int bid = blockIdx.x, tid = threadIdx.x;
    if (bid < NB_ROOTS) {
        // wave-private repack region: 32 tokens x 12 dwords (16B-aligned rows)
        uint32_t* st = (uint32_t*)smem + (tid >> 6) * (32 * 12);
        int wid = tid >> 6, lane = tid & 63;
        int c = lane & 31, h = lane >> 5;
        int bx = bid & 63, by = bid >> 6;
        int tile0 = bx * 16 + wid * 4;       // 4 MFMA tiles = 16 trees per wave
        int w0w   = bx * 64 + wid * 16;      // wave's first tree
        int t0b   = by * 512;
        float lw = np_[0], rw = np_[1], pw = np_[2], dw = np_[3], nb = np_[4];
        const float c2 = 2.885390081777927f;     // 2*log2(e)
        float A1 = (lw + dw) * c2, A2 = pw * c2, A3 = (rw - dw) * c2, A4 = nb * c2;

        bhalf8 af[4];
        #pragma unroll
        for (int tl = 0; tl < 4; ++tl)
            af[tl] = *(const bhalf8*)(selwA + (size_t)((tile0 + tl) * 32 + c) * 16 + h * 8);

        int tok = lane >> 1, half = lane & 1;    // store-phase role (per wave)
        for (int it = 0; it < 16; ++it) {
            int t0 = t0b + it * 32;
            bhalf8 bf = *(const bhalf8*)(basisTB + (size_t)(t0 + c) * 16 + h * 8);
            #pragma unroll
            for (int tl = 0; tl < 4; ++tl) {
                floatx16 z = {0.f,0.f,0.f,0.f,0.f,0.f,0.f,0.f,
                              0.f,0.f,0.f,0.f,0.f,0.f,0.f,0.f};
                floatx16 cc = __builtin_amdgcn_mfma_f32_32x32x16_bf16(af[tl], bf, z, 0, 0, 0);
                float vA[8], vB[8];
                #pragma unroll
                for (int l = 0; l < 8; ++l) { vA[l] = cc[l]; vB[l] = cc[8 + l]; }
                float rA = tree_eval(vA, A1, A2, A3, A4);
                float rB = tree_eval(vB, A1, A2, A3, A4);
                // pair p = tl*2+h -> trees w0w+2p, +1; token c
                st[c * 12 + tl * 2 + h] =
                    (uint32_t)f2bf(rA) | ((uint32_t)f2bf(rB) << 16);
            }
            // wave-synchronous LDS: ds_write -> ds_read ordering via lgkmcnt,
            // no s_barrier needed (private region, single wave)
            uint4 q = *(const uint4*)(st + tok * 12 + half * 4);
            *(uint4*)(roots + (size_t)(t0 + tok) * WTR + w0w + half * 8) = q;
        }
    } else {                               // ---- out_w (W,D) -> owt (D,W) bf16
        float (*tile)[65] = (float (*)[65])smem;
        int b = bid - NB_ROOTS;            // 1024 blocks: 16 d-tiles x 64 w-tiles
        int d0 = (b & 15) * 64, w0 = (b >> 4) * 64;
        int tx = tid & 63, ty = tid >> 6;  // (64, 4)
        #pragma unroll
        for (int i = 0; i < 64; i += 4)
            tile[ty + i][tx] = ow[(size_t)(w0 + ty + i) * DIM + d0 + tx];
        __syncthreads();
        #pragma unroll
        for (int i = 0; i < 64; i += 4)
            owt[(size_t)(d0 + ty + i) * WTR + w0 + tx] = f2bf(tile[tx][ty + i]);
    }
}

// ---- kernel 2: out = roots @ out_w + out_b  (FROZEN from R11: best of 8) -----
// BM=64 BN=64 BK=64, 128-thr blocks (2 waves, wave tile 64x32), 16 KB LDS ->
// grid (64,16) = 1024 blocks = 4/CU, zero atomics, zero conflicts (R6 swizzle).
__global__ __launch_bounds__(128) void k_gemm(const u16* __restrict__ A,
                                              const u16* __restrict__ Bt,
                                              const float* __restrict__ out_b,
                                              float* __restrict__ C) {
    __shared__ __align__(16) u16 smA[64 * 64];    // 8 KB
    __shared__ __align__(16) u16 smB[64 * 64];    // 8 KB
    int tid = threadIdx.x;
    int bm = blockIdx.x * 64, bn = blockIdx.y * 64;
    int lane = tid & 63, wid = tid >> 6;   // 2 waves
    int wn = wid * 32;

    floatx4 acc[4][2];
    #pragma unroll
    for (int i = 0; i < 4; ++i)
        #pragma unroll
        for (int j = 0; j < 2; ++j) acc[i][j] = (floatx4){0.f, 0.f, 0.f, 0.f};

    int ar = tid >> 3;                          // staging row 0..15 (+16/inst)
    int ak = ((tid & 7) ^ (ar & 7)) * 8;        // swizzled source k-chunk
    const u16* gA = A  + (size_t)(bm + ar) * KDIM + ak;
    const u16* gB = Bt + (size_t)(bn + ar) * KDIM + ak;
    char* ldA = (char*)smA + tid * 16;
    char* ldB = (char*)smB + tid * 16;

    int col = lane & 15, quad = lane >> 4, csw = col & 7;

    for (int k0 = 0; k0 < KDIM; k0 += 64) {
        __syncthreads();                        // prev iter's ds_reads done
        load16(gA,                       ldA);
        load16(gA + (size_t)16 * KDIM,   ldA + 2048);
        load16(gA + (size_t)32 * KDIM,   ldA + 4096);
        load16(gA + (size_t)48 * KDIM,   ldA + 6144);
        load16(gB,                       ldB);
        load16(gB + (size_t)16 * KDIM,   ldB + 2048);
        load16(gB + (size_t)32 * KDIM,   ldB + 4096);
        load16(gB + (size_t)48 * KDIM,   ldB + 6144);
        gA += 64; gB += 64;
        __syncthreads();                        // drain (hidden by 4 blk/CU)

        #pragma unroll
        for (int kk = 0; kk < 2; ++kk) {
            int kc = kk * 4 + quad;
            bhalf8 af[4], bf[2];
            #pragma unroll
            for (int i = 0; i < 4; ++i)
                af[i] = *(const bhalf8*)(smA + ((i * 16 + col) * 8 + (kc ^ csw)) * 8);
            #pragma unroll
            for (int j = 0; j < 2; ++j)
                bf[j] = *(const bhalf8*)(smB + ((wn + j * 16 + col) * 8 + (kc ^ csw)) * 8);
            #pragma unroll
            for (int i = 0; i < 4; ++i)
                #pragma unroll
                for (int j = 0; j < 2; ++j)
                    acc[i][j] = __builtin_amdgcn_mfma_f32_16x16x32_bf16(
                        af[i], bf[j], acc[i][j], 0, 0, 0);
        }
    }

    #pragma unroll
    for (int j = 0; j < 2; ++j) {
        int n = bn + wn + j * 16 + col;
        float bv = out_b[n];
        #pragma unroll
        for (int i = 0; i < 4; ++i) {
            int m0 = bm + i * 16 + quad * 4;
            #pragma unroll
            for (int r = 0; r < 4; ++r)
                C[(size_t)(m0 + r) * DIM + n] = acc[i][j][r] + bv;
        }
    }
}

// ---------------- launcher ----------------------------------------------------
extern "C" void kernel_launch(void* const* d_in, const int* in_sizes, int n_in,
                              void* d_out, int out_size, void* d_ws, size_t ws_size,
                              hipStream_t stream) {
    const float* hidden      = (const float*)d_in[0];
    const float* slot_w      = (const float*)d_in[1];
    const float* slot_b      = (const float*)d_in[2];
    const float* leaf_logits = (const float*)d_in[3];
    const float* node_params = (const float*)d_in[4];
    const float* out_w       = (const float*)d_in[5];
    const float* out_b       = (const float*)d_in[6];
    float* out = (float*)d_out;

    char* ws = (char*)d_ws;
    u16* selwA   = (u16*)ws;                          // 32768*32B   = 1048576
    u16* basisTB = (u16*)(ws + 1048576);              // 4096*32B    = 131072
    u16* outwt   = (u16*)(ws + 1212416);              // 1024*4096*2 = 8388608
    u16* roots   = (u16*)(ws + 9601024);              // 4096*4096*2 = 33554432

    k_prep <<<NB_SEL + NB_BASIS, 256, 0, stream>>>(
        leaf_logits, selwA, slot_w, slot_b, hidden, basisTB);
    k_roots<<<NB_ROOTS + NB_OWT, 256, 0, stream>>>(
        selwA, basisTB, node_params, roots, out_w, outwt);
    k_gemm <<<dim3(BSZ / 64, DIM / 64), 128, 0, stream>>>(roots, outwt, out_b, out);
}